// Round 11
// baseline (197.031 us; speedup 1.0000x reference)
//
#include <hip/hip_runtime.h>
#include <hip/hip_bf16.h>
#include <hip/hip_fp16.h>

#define HID 256
#define HEADS 4
#define DH 64
#define SLOPE 0.2f
#define NBMAX 512   // max buckets (Nn<=65536)
#define BCAP 4096   // max edges per bucket

typedef __attribute__((ext_vector_type(8))) _Float16 f16x8;
typedef __attribute__((ext_vector_type(4))) float f32x4;

__device__ inline float leaky(float x) { return x >= 0.f ? x : SLOPE * x; }

// ---------- K0: Wt[n][k] = fp16(W[k][n]); block 0 zeros bucket_cnt ----------
__global__ __launch_bounds__(256) void transpose_w(const float* __restrict__ W,
                                                   _Float16* __restrict__ Wt,
                                                   int* __restrict__ bucket_cnt) {
  int n = blockIdx.x;
  int k = threadIdx.x;
  Wt[n * HID + k] = (_Float16)W[(size_t)k * HID + n];
  if (n == 0) {
    bucket_cnt[k] = 0;
    bucket_cnt[k + 256] = 0;
  }
}

// ---------- K1: LDS-free GEMM. block = 32 rows; wave = one head (64 cols). ----------
// A-frags straight from X (fp32->fp16 in regs, line-coalesced); B-frags from
// L2-resident Wt. No LDS, no barriers -> pure occupancy latency hiding.
__global__ __launch_bounds__(256) void gemm_direct(const float* __restrict__ X,
                                                   const _Float16* __restrict__ Wt,
                                                   const float* __restrict__ att_src,
                                                   const float* __restrict__ att_dst,
                                                   _Float16* __restrict__ Hp,
                                                   float* __restrict__ a_s,
                                                   float* __restrict__ a_d, int M) {
  const int head = threadIdx.x >> 6;      // wave = head
  const int l = threadIdx.x & 63;
  const int row0 = blockIdx.x * 32;
  const int lr = l & 15;                  // fragment row/col index
  const int lk = l >> 4;                  // k-group 0..3

  f32x4 acc[2][4] = {};

  for (int ks = 0; ks < 8; ++ks) {
    f16x8 af[2];
#pragma unroll
    for (int mt = 0; mt < 2; ++mt) {
      const int row = row0 + mt * 16 + lr;
      float4 v0 = make_float4(0.f, 0.f, 0.f, 0.f), v1 = v0;
      if (row < M) {
        const float* p = X + (size_t)row * HID + ks * 32 + lk * 8;
        v0 = *(const float4*)p;
        v1 = *(const float4*)(p + 4);
      }
      _Float16 tmp[8] = {(_Float16)v0.x, (_Float16)v0.y, (_Float16)v0.z, (_Float16)v0.w,
                         (_Float16)v1.x, (_Float16)v1.y, (_Float16)v1.z, (_Float16)v1.w};
      af[mt] = *(const f16x8*)tmp;
    }
#pragma unroll
    for (int nt = 0; nt < 4; ++nt) {
      const f16x8 bfr = *(const f16x8*)(Wt + (size_t)(head * 64 + nt * 16 + lr) * HID
                                        + ks * 32 + lk * 8);
#pragma unroll
      for (int mt = 0; mt < 2; ++mt)
        acc[mt][nt] = __builtin_amdgcn_mfma_f32_16x16x32_f16(af[mt], bfr, acc[mt][nt], 0, 0, 0);
    }
  }

  // fused attention coefficients (head-major a_s/a_d)
  float as_v[4], ad_v[4];
#pragma unroll
  for (int nt = 0; nt < 4; ++nt) {
    as_v[nt] = att_src[head * DH + nt * 16 + lr];
    ad_v[nt] = att_dst[head * DH + nt * 16 + lr];
  }
#pragma unroll
  for (int mt = 0; mt < 2; ++mt) {
#pragma unroll
    for (int reg = 0; reg < 4; ++reg) {
      float ps = 0.f, pd = 0.f;
#pragma unroll
      for (int nt = 0; nt < 4; ++nt) {
        ps += acc[mt][nt][reg] * as_v[nt];
        pd += acc[mt][nt][reg] * ad_v[nt];
      }
#pragma unroll
      for (int off = 1; off < 16; off <<= 1) {
        ps += __shfl_xor(ps, off, 64);
        pd += __shfl_xor(pd, off, 64);
      }
      const int row = row0 + mt * 16 + lk * 4 + reg;
      if (lr == 0 && row < M) {
        a_s[(size_t)head * M + row] = ps;
        a_d[(size_t)head * M + row] = pd;
      }
    }
  }

  // store Hp head-major: Hp[head][row][dh]
#pragma unroll
  for (int mt = 0; mt < 2; ++mt) {
#pragma unroll
    for (int nt = 0; nt < 4; ++nt) {
      const int dh = nt * 16 + lr;
#pragma unroll
      for (int reg = 0; reg < 4; ++reg) {
        const int row = row0 + mt * 16 + lk * 4 + reg;
        if (row < M)
          Hp[((size_t)head * M + row) * DH + dh] = (_Float16)acc[mt][nt][reg];
      }
    }
  }
}

// ---------- A1: bucket histogram (bucket = dst>>7), LDS-aggregated ----------
__global__ __launch_bounds__(256) void bucket_hist(const int* __restrict__ ei, int E, int Etot,
                                                   int* __restrict__ bucket_cnt, int NB) {
  __shared__ int h[NBMAX];
  for (int i = threadIdx.x; i < NB; i += 256) h[i] = 0;
  __syncthreads();
  const int g0 = blockIdx.x * 1024;
#pragma unroll
  for (int j = 0; j < 4; ++j) {
    const int e0 = (g0 + j * 256 + threadIdx.x) * 4;
    if (e0 >= Etot) continue;
    if (e0 >= E) {
#pragma unroll
      for (int k = 0; k < 4; ++k) atomicAdd(&h[(e0 - E + k) >> 7], 1);
    } else {
      const int4 d4 = *(const int4*)(ei + E + e0);
      atomicAdd(&h[d4.x >> 7], 1);
      atomicAdd(&h[d4.y >> 7], 1);
      atomicAdd(&h[d4.z >> 7], 1);
      atomicAdd(&h[d4.w >> 7], 1);
    }
  }
  __syncthreads();
  for (int i = threadIdx.x; i < NB; i += 256)
    if (h[i]) atomicAdd(&bucket_cnt[i], h[i]);
}

// ---------- A2: scan bucket counts -> base & cursor ----------
__global__ __launch_bounds__(512) void scan_buckets(const int* __restrict__ bucket_cnt,
                                                    int* __restrict__ bucket_base,
                                                    int* __restrict__ bucket_cursor,
                                                    int* __restrict__ offsets,
                                                    int Nn, int Etot, int NB) {
  __shared__ int h[512];
  const int tid = threadIdx.x;
  const int v = (tid < NB) ? bucket_cnt[tid] : 0;
  h[tid] = v;
  __syncthreads();
#pragma unroll
  for (int off = 1; off < 512; off <<= 1) {
    const int t = (tid >= off) ? h[tid - off] : 0;
    __syncthreads();
    h[tid] += t;
    __syncthreads();
  }
  if (tid < NB) {
    const int base = h[tid] - v;
    bucket_base[tid] = base;
    bucket_cursor[tid] = base;
  }
  if (tid == 0) offsets[Nn] = Etot;
}

// ---------- A3: scatter packed (dn_local<<16 | src) into block-reserved runs ----------
__global__ __launch_bounds__(256) void scatter_tmp(const int* __restrict__ ei, int E, int Etot,
                                                   int* __restrict__ bucket_cursor,
                                                   unsigned* __restrict__ tmp, int NB) {
  __shared__ int h[NBMAX];
  __shared__ int cur[NBMAX];
  for (int i = threadIdx.x; i < NB; i += 256) h[i] = 0;
  __syncthreads();
  const int g0 = blockIdx.x * 1024;
#pragma unroll
  for (int j = 0; j < 4; ++j) {
    const int e0 = (g0 + j * 256 + threadIdx.x) * 4;
    if (e0 >= Etot) continue;
    if (e0 >= E) {
#pragma unroll
      for (int k = 0; k < 4; ++k) atomicAdd(&h[(e0 - E + k) >> 7], 1);
    } else {
      const int4 d4 = *(const int4*)(ei + E + e0);
      atomicAdd(&h[d4.x >> 7], 1);
      atomicAdd(&h[d4.y >> 7], 1);
      atomicAdd(&h[d4.z >> 7], 1);
      atomicAdd(&h[d4.w >> 7], 1);
    }
  }
  __syncthreads();
  for (int i = threadIdx.x; i < NB; i += 256)
    cur[i] = h[i] ? atomicAdd(&bucket_cursor[i], h[i]) : 0;
  __syncthreads();
#pragma unroll
  for (int j = 0; j < 4; ++j) {
    const int e0 = (g0 + j * 256 + threadIdx.x) * 4;
    if (e0 >= Etot) continue;
    int s[4], dn[4];
    if (e0 >= E) {
#pragma unroll
      for (int k = 0; k < 4; ++k) { s[k] = e0 - E + k; dn[k] = s[k]; }
    } else {
      const int4 s4 = *(const int4*)(ei + e0);
      const int4 d4 = *(const int4*)(ei + E + e0);
      s[0] = s4.x; s[1] = s4.y; s[2] = s4.z; s[3] = s4.w;
      dn[0] = d4.x; dn[1] = d4.y; dn[2] = d4.z; dn[3] = d4.w;
    }
#pragma unroll
    for (int k = 0; k < 4; ++k) {
      const int b = dn[k] >> 7;
      const int pos = atomicAdd(&cur[b], 1);
      tmp[pos] = (unsigned)s[k] | ((unsigned)(dn[k] & 127) << 16);
    }
  }
}

// ---------- B: per-bucket counting sort in LDS -> offsets + csr_src ----------
__global__ __launch_bounds__(256) void csr_build(const unsigned* __restrict__ tmp,
                                                 const int* __restrict__ bucket_base,
                                                 const int* __restrict__ bucket_cursor,
                                                 int* __restrict__ offsets,
                                                 int* __restrict__ csr_src, int Nn) {
  __shared__ int h[128], cur[128];
  __shared__ int cs[BCAP];
  const int b = blockIdx.x;
  const int start = bucket_base[b];
  const int cnt = min(bucket_cursor[b] - start, BCAP);
  const int tid = threadIdx.x;
  if (tid < 128) h[tid] = 0;
  __syncthreads();
  for (int i = tid; i < cnt; i += 256)
    atomicAdd(&h[tmp[start + i] >> 16], 1);
  __syncthreads();
  const int own = (tid < 128) ? h[tid] : 0;
#pragma unroll
  for (int off = 1; off < 128; off <<= 1) {
    const int t = (tid < 128 && tid >= off) ? h[tid - off] : 0;
    __syncthreads();
    if (tid < 128) h[tid] += t;
    __syncthreads();
  }
  if (tid < 128) {
    const int excl = h[tid] - own;
    cur[tid] = excl;
    const int n = b * 128 + tid;
    if (n < Nn) offsets[n] = start + excl;
  }
  __syncthreads();
  for (int i = tid; i < cnt; i += 256) {
    const unsigned p = tmp[start + i];
    const int pos = atomicAdd(&cur[p >> 16], 1);
    cs[pos] = (int)(p & 0xffffu);
  }
  __syncthreads();
  for (int i = tid; i < cnt; i += 256)
    csr_src[start + i] = cs[i];
}

// ---------- K6: fused softmax + aggregate, head-split (head-major Hp) ----------
__global__ __launch_bounds__(256) void gat_agg2(const int* __restrict__ offsets,
                                                const int* __restrict__ csr_src,
                                                const float* __restrict__ a_s,
                                                const float* __restrict__ a_d,
                                                const _Float16* __restrict__ Hp,
                                                const float* __restrict__ bias,
                                                float* __restrict__ out, int Nn, int nbNode) {
  const int head = blockIdx.x / nbNode;
  const int nb   = blockIdx.x - head * nbNode;
  const int wave = threadIdx.x >> 6;
  const int lane = threadIdx.x & 63;
  const int half = lane >> 5;
  const int hl   = lane & 31;
  const int g2   = hl >> 3;
  const int sl   = hl & 7;
  const int n    = nb * 8 + wave * 2 + half;

  int start = 0, end = 0;
  if (n < Nn) { start = offsets[n]; end = offsets[n + 1]; }
  const float* __restrict__ as_h = a_s + (size_t)head * Nn;
  const float adn = (n < Nn) ? a_d[(size_t)head * Nn + n] : 0.f;
  const _Float16* __restrict__ Hh = Hp + (size_t)head * Nn * DH + sl * 8;

  float m = -INFINITY, l = 0.f;
  __half2 acc[4];
#pragma unroll
  for (int j = 0; j < 4; ++j) acc[j] = __float2half2_rn(0.f);

  const int nChunk = (end - start + 31) >> 5;
  for (int c = 0; c < nChunk; ++c) {
    const int base = start + c * 32;
    const int cnt = min(32, end - base);
    const int idx = min(base + hl, end - 1);
    const int src = csr_src[idx];
    const float lg = leaky(as_h[src] + adn);
    const float logit = (hl < cnt) ? lg : -INFINITY;

    float cm = logit;
#pragma unroll
    for (int off = 16; off > 0; off >>= 1) cm = fmaxf(cm, __shfl_xor(cm, off, 64));
    const float nm = fmaxf(m, cm);
    const float scale = __expf(m - nm);
    const __half2 s2 = __float2half2_rn(scale);
#pragma unroll
    for (int j = 0; j < 4; ++j) acc[j] = __hmul2(acc[j], s2);
    l *= scale;
    const float p = __expf(logit - nm);
    float psum = p;
#pragma unroll
    for (int off = 16; off > 0; off >>= 1) psum += __shfl_xor(psum, off, 64);
    l += psum;
    m = nm;

    const unsigned combo = (unsigned)src |
                           ((unsigned)__half_as_ushort(__float2half(p)) << 16);
    const int nIt = (cnt + 3) >> 2;
#pragma unroll 4
    for (int i = 0; i < nIt; ++i) {
      const int e = i * 4 + g2;
      const unsigned cc = (unsigned)__shfl((int)combo, half * 32 + e, 64);
      const unsigned se = cc & 0xffffu;
      const __half ah = __ushort_as_half((unsigned short)(cc >> 16));
      const __half2 a2 = __halves2half2(ah, ah);
      const uint4 hv = *(const uint4*)(Hh + (size_t)se * DH);
      acc[0] = __hfma2(a2, *(const __half2*)&hv.x, acc[0]);
      acc[1] = __hfma2(a2, *(const __half2*)&hv.y, acc[1]);
      acc[2] = __hfma2(a2, *(const __half2*)&hv.z, acc[2]);
      acc[3] = __hfma2(a2, *(const __half2*)&hv.w, acc[3]);
    }
  }
#pragma unroll
  for (int off = 8; off <= 16; off <<= 1)
#pragma unroll
    for (int j = 0; j < 4; ++j) {
      int tbits = __shfl_xor(*(const int*)&acc[j], off, 64);
      acc[j] = __hadd2(acc[j], *(const __half2*)&tbits);
    }

  if (hl < 8 && n < Nn) {
    const float inv = 1.f / (l + 1e-16f);
    float v[8];
#pragma unroll
    for (int j = 0; j < 4; ++j) {
      v[2 * j]     = __low2float(acc[j]);
      v[2 * j + 1] = __high2float(acc[j]);
    }
#pragma unroll
    for (int j = 0; j < 8; ++j)
      v[j] = fmaxf(v[j] * inv + bias[head * DH + sl * 8 + j], 0.f);
    float* op = out + (size_t)n * HID + head * DH + sl * 8;
    *(float4*)op = make_float4(v[0], v[1], v[2], v[3]);
    *(float4*)(op + 4) = make_float4(v[4], v[5], v[6], v[7]);
  }
}

extern "C" void kernel_launch(void* const* d_in, const int* in_sizes, int n_in,
                              void* d_out, int out_size, void* d_ws, size_t ws_size,
                              hipStream_t stream) {
  const float* x       = (const float*)d_in[0];
  const float* Wm      = (const float*)d_in[1];
  const float* att_src = (const float*)d_in[2];
  const float* att_dst = (const float*)d_in[3];
  const float* bias    = (const float*)d_in[4];
  const int*   ei      = (const int*)d_in[5];

  const int Nn   = in_sizes[0] / HID;   // 50000
  const int E    = in_sizes[5] / 2;     // 1200000
  const int Etot = E + Nn;              // 1250000
  const int NB   = (Nn + 127) >> 7;     // 391

  float* out = (float*)d_out;

  _Float16* Hp    = (_Float16*)d_ws;                     // [4][Nn][64] fp16
  _Float16* Wt    = Hp + (size_t)HEADS * Nn * DH;        // 256*256 fp16
  float* a_s      = (float*)(Wt + HID * HID);            // [4][Nn]
  float* a_d      = a_s + (size_t)HEADS * Nn;
  int*   offsets  = (int*)(a_d + (size_t)HEADS * Nn);    // Nn+1
  int*   bucket_cnt    = offsets + (Nn + 1);
  int*   bucket_base   = bucket_cnt + NBMAX;
  int*   bucket_cursor = bucket_base + NBMAX;
  unsigned* tmp   = (unsigned*)(bucket_cursor + NBMAX);  // Etot u32
  int*   csr_src  = (int*)(tmp + Etot);                  // Etot

  const int nbNode = (Nn + 7) / 8;       // 6250
  const int nbEdge = (Etot + 4095) / 4096;  // 306

  transpose_w<<<HID, HID, 0, stream>>>(Wm, Wt, bucket_cnt);
  gemm_direct<<<(Nn + 31) / 32, 256, 0, stream>>>(x, Wt, att_src, att_dst,
                                                  Hp, a_s, a_d, Nn);

  bucket_hist<<<nbEdge, 256, 0, stream>>>(ei, E, Etot, bucket_cnt, NB);
  scan_buckets<<<1, 512, 0, stream>>>(bucket_cnt, bucket_base, bucket_cursor,
                                      offsets, Nn, Etot, NB);
  scatter_tmp<<<nbEdge, 256, 0, stream>>>(ei, E, Etot, bucket_cursor, tmp, NB);
  csr_build<<<NB, 256, 0, stream>>>(tmp, bucket_base, bucket_cursor,
                                    offsets, csr_src, Nn);
  gat_agg2<<<HEADS * nbNode, 256, 0, stream>>>(offsets, csr_src, a_s, a_d, Hp, bias,
                                               out, Nn, nbNode);
}

// Round 12
// 179.707 us; speedup vs baseline: 1.0964x; 1.0964x over previous
//
#include <hip/hip_runtime.h>
#include <hip/hip_bf16.h>
#include <hip/hip_fp16.h>

#define HID 256
#define HEADS 4
#define DH 64
#define SLOPE 0.2f
#define NBMAX 512   // max buckets (Nn<=65536)
#define BCAP 4096   // max edges per bucket

typedef __attribute__((ext_vector_type(8))) _Float16 f16x8;
typedef __attribute__((ext_vector_type(4))) float f32x4;

__device__ inline float leaky(float x) { return x >= 0.f ? x : SLOPE * x; }

// ---------- K0: Wt[n][k] = fp16(W[k][n]); block 0 zeros bucket_cnt ----------
__global__ __launch_bounds__(256) void transpose_w(const float* __restrict__ W,
                                                   _Float16* __restrict__ Wt,
                                                   int* __restrict__ bucket_cnt) {
  int n = blockIdx.x;
  int k = threadIdx.x;
  Wt[n * HID + k] = (_Float16)W[(size_t)k * HID + n];
  if (n == 0) {
    bucket_cnt[k] = 0;
    bucket_cnt[k + 256] = 0;
  }
}

// ---------- K1: GEMM, A-tile staged ONCE in LDS, B from L2-resident Wt ----------
// block = 32 rows x 4 head-waves, one barrier total. X read exactly once.
__global__ __launch_bounds__(256) void gemm_tile(const float* __restrict__ X,
                                                 const _Float16* __restrict__ Wt,
                                                 const float* __restrict__ att_src,
                                                 const float* __restrict__ att_dst,
                                                 _Float16* __restrict__ Hp,
                                                 float* __restrict__ a_s,
                                                 float* __restrict__ a_d, int M) {
  __shared__ _Float16 sA[8][32][40];      // [ks][row][32+pad]
  const int t = threadIdx.x;
  const int head = t >> 6;                // wave = head
  const int l = t & 63;
  const int lr = l & 15;
  const int lk = l >> 4;
  const int row0 = blockIdx.x * 32;

  // stage full A tile: thread t loads row t>>3, ks-chunk t&7 (128 B contiguous)
  {
    const int r = t >> 3;
    const int ksb = t & 7;
    const int gr = row0 + r;
    _Float16 tmp[32];
    if (gr < M) {
      const float* p = X + (size_t)gr * HID + ksb * 32;
#pragma unroll
      for (int j = 0; j < 8; ++j) {
        const float4 v = *(const float4*)(p + j * 4);
        tmp[j * 4 + 0] = (_Float16)v.x;
        tmp[j * 4 + 1] = (_Float16)v.y;
        tmp[j * 4 + 2] = (_Float16)v.z;
        tmp[j * 4 + 3] = (_Float16)v.w;
      }
    } else {
#pragma unroll
      for (int j = 0; j < 32; ++j) tmp[j] = (_Float16)0.f;
    }
#pragma unroll
    for (int j = 0; j < 4; ++j)
      *(uint4*)&sA[ksb][r][j * 8] = *(const uint4*)&tmp[j * 8];
  }
  __syncthreads();

  f32x4 acc[2][4] = {};
#pragma unroll
  for (int ks = 0; ks < 8; ++ks) {
    f16x8 af[2];
#pragma unroll
    for (int mt = 0; mt < 2; ++mt)
      af[mt] = *(const f16x8*)&sA[ks][mt * 16 + lr][lk * 8];
#pragma unroll
    for (int nt = 0; nt < 4; ++nt) {
      const f16x8 bfr = *(const f16x8*)(Wt + (size_t)(head * 64 + nt * 16 + lr) * HID
                                        + ks * 32 + lk * 8);
#pragma unroll
      for (int mt = 0; mt < 2; ++mt)
        acc[mt][nt] = __builtin_amdgcn_mfma_f32_16x16x32_f16(af[mt], bfr, acc[mt][nt], 0, 0, 0);
    }
  }

  // fused attention coefficients (head-major a_s/a_d)
  float as_v[4], ad_v[4];
#pragma unroll
  for (int nt = 0; nt < 4; ++nt) {
    as_v[nt] = att_src[head * DH + nt * 16 + lr];
    ad_v[nt] = att_dst[head * DH + nt * 16 + lr];
  }
#pragma unroll
  for (int mt = 0; mt < 2; ++mt) {
#pragma unroll
    for (int reg = 0; reg < 4; ++reg) {
      float ps = 0.f, pd = 0.f;
#pragma unroll
      for (int nt = 0; nt < 4; ++nt) {
        ps += acc[mt][nt][reg] * as_v[nt];
        pd += acc[mt][nt][reg] * ad_v[nt];
      }
#pragma unroll
      for (int off = 1; off < 16; off <<= 1) {
        ps += __shfl_xor(ps, off, 64);
        pd += __shfl_xor(pd, off, 64);
      }
      const int row = row0 + mt * 16 + lk * 4 + reg;
      if (lr == 0 && row < M) {
        a_s[(size_t)head * M + row] = ps;
        a_d[(size_t)head * M + row] = pd;
      }
    }
  }

  // store Hp head-major: Hp[head][row][dh]
#pragma unroll
  for (int mt = 0; mt < 2; ++mt) {
#pragma unroll
    for (int nt = 0; nt < 4; ++nt) {
      const int dh = nt * 16 + lr;
#pragma unroll
      for (int reg = 0; reg < 4; ++reg) {
        const int row = row0 + mt * 16 + lk * 4 + reg;
        if (row < M)
          Hp[((size_t)head * M + row) * DH + dh] = (_Float16)acc[mt][nt][reg];
      }
    }
  }
}

// ---------- A1: bucket histogram (bucket = dst>>7), LDS-aggregated ----------
__global__ __launch_bounds__(256) void bucket_hist(const int* __restrict__ ei, int E, int Etot,
                                                   int* __restrict__ bucket_cnt, int NB) {
  __shared__ int h[NBMAX];
  for (int i = threadIdx.x; i < NB; i += 256) h[i] = 0;
  __syncthreads();
  const int g0 = blockIdx.x * 1024;
#pragma unroll
  for (int j = 0; j < 4; ++j) {
    const int e0 = (g0 + j * 256 + threadIdx.x) * 4;
    if (e0 >= Etot) continue;
    if (e0 >= E) {
#pragma unroll
      for (int k = 0; k < 4; ++k) atomicAdd(&h[(e0 - E + k) >> 7], 1);
    } else {
      const int4 d4 = *(const int4*)(ei + E + e0);
      atomicAdd(&h[d4.x >> 7], 1);
      atomicAdd(&h[d4.y >> 7], 1);
      atomicAdd(&h[d4.z >> 7], 1);
      atomicAdd(&h[d4.w >> 7], 1);
    }
  }
  __syncthreads();
  for (int i = threadIdx.x; i < NB; i += 256)
    if (h[i]) atomicAdd(&bucket_cnt[i], h[i]);
}

// ---------- A2: scan bucket counts -> base & cursor ----------
__global__ __launch_bounds__(512) void scan_buckets(const int* __restrict__ bucket_cnt,
                                                    int* __restrict__ bucket_base,
                                                    int* __restrict__ bucket_cursor,
                                                    int* __restrict__ offsets,
                                                    int Nn, int Etot, int NB) {
  __shared__ int h[512];
  const int tid = threadIdx.x;
  const int v = (tid < NB) ? bucket_cnt[tid] : 0;
  h[tid] = v;
  __syncthreads();
#pragma unroll
  for (int off = 1; off < 512; off <<= 1) {
    const int t = (tid >= off) ? h[tid - off] : 0;
    __syncthreads();
    h[tid] += t;
    __syncthreads();
  }
  if (tid < NB) {
    const int base = h[tid] - v;
    bucket_base[tid] = base;
    bucket_cursor[tid] = base;
  }
  if (tid == 0) offsets[Nn] = Etot;
}

// ---------- A3: scatter packed (dn_local<<16 | src) into block-reserved runs ----------
__global__ __launch_bounds__(256) void scatter_tmp(const int* __restrict__ ei, int E, int Etot,
                                                   int* __restrict__ bucket_cursor,
                                                   unsigned* __restrict__ tmp, int NB) {
  __shared__ int h[NBMAX];
  __shared__ int cur[NBMAX];
  for (int i = threadIdx.x; i < NB; i += 256) h[i] = 0;
  __syncthreads();
  const int g0 = blockIdx.x * 1024;
#pragma unroll
  for (int j = 0; j < 4; ++j) {
    const int e0 = (g0 + j * 256 + threadIdx.x) * 4;
    if (e0 >= Etot) continue;
    if (e0 >= E) {
#pragma unroll
      for (int k = 0; k < 4; ++k) atomicAdd(&h[(e0 - E + k) >> 7], 1);
    } else {
      const int4 d4 = *(const int4*)(ei + E + e0);
      atomicAdd(&h[d4.x >> 7], 1);
      atomicAdd(&h[d4.y >> 7], 1);
      atomicAdd(&h[d4.z >> 7], 1);
      atomicAdd(&h[d4.w >> 7], 1);
    }
  }
  __syncthreads();
  for (int i = threadIdx.x; i < NB; i += 256)
    cur[i] = h[i] ? atomicAdd(&bucket_cursor[i], h[i]) : 0;
  __syncthreads();
#pragma unroll
  for (int j = 0; j < 4; ++j) {
    const int e0 = (g0 + j * 256 + threadIdx.x) * 4;
    if (e0 >= Etot) continue;
    int s[4], dn[4];
    if (e0 >= E) {
#pragma unroll
      for (int k = 0; k < 4; ++k) { s[k] = e0 - E + k; dn[k] = s[k]; }
    } else {
      const int4 s4 = *(const int4*)(ei + e0);
      const int4 d4 = *(const int4*)(ei + E + e0);
      s[0] = s4.x; s[1] = s4.y; s[2] = s4.z; s[3] = s4.w;
      dn[0] = d4.x; dn[1] = d4.y; dn[2] = d4.z; dn[3] = d4.w;
    }
#pragma unroll
    for (int k = 0; k < 4; ++k) {
      const int b = dn[k] >> 7;
      const int pos = atomicAdd(&cur[b], 1);
      tmp[pos] = (unsigned)s[k] | ((unsigned)(dn[k] & 127) << 16);
    }
  }
}

// ---------- B: per-bucket counting sort in LDS -> offsets + csr_src ----------
__global__ __launch_bounds__(256) void csr_build(const unsigned* __restrict__ tmp,
                                                 const int* __restrict__ bucket_base,
                                                 const int* __restrict__ bucket_cursor,
                                                 int* __restrict__ offsets,
                                                 int* __restrict__ csr_src, int Nn) {
  __shared__ int h[128], cur[128];
  __shared__ int cs[BCAP];
  const int b = blockIdx.x;
  const int start = bucket_base[b];
  const int cnt = min(bucket_cursor[b] - start, BCAP);
  const int tid = threadIdx.x;
  if (tid < 128) h[tid] = 0;
  __syncthreads();
  for (int i = tid; i < cnt; i += 256)
    atomicAdd(&h[tmp[start + i] >> 16], 1);
  __syncthreads();
  const int own = (tid < 128) ? h[tid] : 0;
#pragma unroll
  for (int off = 1; off < 128; off <<= 1) {
    const int t = (tid < 128 && tid >= off) ? h[tid - off] : 0;
    __syncthreads();
    if (tid < 128) h[tid] += t;
    __syncthreads();
  }
  if (tid < 128) {
    const int excl = h[tid] - own;
    cur[tid] = excl;
    const int n = b * 128 + tid;
    if (n < Nn) offsets[n] = start + excl;
  }
  __syncthreads();
  for (int i = tid; i < cnt; i += 256) {
    const unsigned p = tmp[start + i];
    const int pos = atomicAdd(&cur[p >> 16], 1);
    cs[pos] = (int)(p & 0xffffu);
  }
  __syncthreads();
  for (int i = tid; i < cnt; i += 256)
    csr_src[start + i] = cs[i];
}

// ---------- K6: fused softmax + aggregate, head-split (head-major Hp) ----------
__global__ __launch_bounds__(256) void gat_agg2(const int* __restrict__ offsets,
                                                const int* __restrict__ csr_src,
                                                const float* __restrict__ a_s,
                                                const float* __restrict__ a_d,
                                                const _Float16* __restrict__ Hp,
                                                const float* __restrict__ bias,
                                                float* __restrict__ out, int Nn, int nbNode) {
  const int head = blockIdx.x / nbNode;
  const int nb   = blockIdx.x - head * nbNode;
  const int wave = threadIdx.x >> 6;
  const int lane = threadIdx.x & 63;
  const int half = lane >> 5;
  const int hl   = lane & 31;
  const int g2   = hl >> 3;
  const int sl   = hl & 7;
  const int n    = nb * 8 + wave * 2 + half;

  int start = 0, end = 0;
  if (n < Nn) { start = offsets[n]; end = offsets[n + 1]; }
  const float* __restrict__ as_h = a_s + (size_t)head * Nn;
  const float adn = (n < Nn) ? a_d[(size_t)head * Nn + n] : 0.f;
  const _Float16* __restrict__ Hh = Hp + (size_t)head * Nn * DH + sl * 8;

  float m = -INFINITY, l = 0.f;
  __half2 acc[4];
#pragma unroll
  for (int j = 0; j < 4; ++j) acc[j] = __float2half2_rn(0.f);

  const int nChunk = (end - start + 31) >> 5;
  for (int c = 0; c < nChunk; ++c) {
    const int base = start + c * 32;
    const int cnt = min(32, end - base);
    const int idx = min(base + hl, end - 1);
    const int src = csr_src[idx];
    const float lg = leaky(as_h[src] + adn);
    const float logit = (hl < cnt) ? lg : -INFINITY;

    float cm = logit;
#pragma unroll
    for (int off = 16; off > 0; off >>= 1) cm = fmaxf(cm, __shfl_xor(cm, off, 64));
    const float nm = fmaxf(m, cm);
    const float scale = __expf(m - nm);
    const __half2 s2 = __float2half2_rn(scale);
#pragma unroll
    for (int j = 0; j < 4; ++j) acc[j] = __hmul2(acc[j], s2);
    l *= scale;
    const float p = __expf(logit - nm);
    float psum = p;
#pragma unroll
    for (int off = 16; off > 0; off >>= 1) psum += __shfl_xor(psum, off, 64);
    l += psum;
    m = nm;

    const unsigned combo = (unsigned)src |
                           ((unsigned)__half_as_ushort(__float2half(p)) << 16);
    const int nIt = (cnt + 3) >> 2;
#pragma unroll 4
    for (int i = 0; i < nIt; ++i) {
      const int e = i * 4 + g2;
      const unsigned cc = (unsigned)__shfl((int)combo, half * 32 + e, 64);
      const unsigned se = cc & 0xffffu;
      const __half ah = __ushort_as_half((unsigned short)(cc >> 16));
      const __half2 a2 = __halves2half2(ah, ah);
      const uint4 hv = *(const uint4*)(Hh + (size_t)se * DH);
      acc[0] = __hfma2(a2, *(const __half2*)&hv.x, acc[0]);
      acc[1] = __hfma2(a2, *(const __half2*)&hv.y, acc[1]);
      acc[2] = __hfma2(a2, *(const __half2*)&hv.z, acc[2]);
      acc[3] = __hfma2(a2, *(const __half2*)&hv.w, acc[3]);
    }
  }
#pragma unroll
  for (int off = 8; off <= 16; off <<= 1)
#pragma unroll
    for (int j = 0; j < 4; ++j) {
      int tbits = __shfl_xor(*(const int*)&acc[j], off, 64);
      acc[j] = __hadd2(acc[j], *(const __half2*)&tbits);
    }

  if (hl < 8 && n < Nn) {
    const float inv = 1.f / (l + 1e-16f);
    float v[8];
#pragma unroll
    for (int j = 0; j < 4; ++j) {
      v[2 * j]     = __low2float(acc[j]);
      v[2 * j + 1] = __high2float(acc[j]);
    }
#pragma unroll
    for (int j = 0; j < 8; ++j)
      v[j] = fmaxf(v[j] * inv + bias[head * DH + sl * 8 + j], 0.f);
    float* op = out + (size_t)n * HID + head * DH + sl * 8;
    *(float4*)op = make_float4(v[0], v[1], v[2], v[3]);
    *(float4*)(op + 4) = make_float4(v[4], v[5], v[6], v[7]);
  }
}

extern "C" void kernel_launch(void* const* d_in, const int* in_sizes, int n_in,
                              void* d_out, int out_size, void* d_ws, size_t ws_size,
                              hipStream_t stream) {
  const float* x       = (const float*)d_in[0];
  const float* Wm      = (const float*)d_in[1];
  const float* att_src = (const float*)d_in[2];
  const float* att_dst = (const float*)d_in[3];
  const float* bias    = (const float*)d_in[4];
  const int*   ei      = (const int*)d_in[5];

  const int Nn   = in_sizes[0] / HID;   // 50000
  const int E    = in_sizes[5] / 2;     // 1200000
  const int Etot = E + Nn;              // 1250000
  const int NB   = (Nn + 127) >> 7;     // 391

  float* out = (float*)d_out;

  _Float16* Hp    = (_Float16*)d_ws;                     // [4][Nn][64] fp16
  _Float16* Wt    = Hp + (size_t)HEADS * Nn * DH;        // 256*256 fp16
  float* a_s      = (float*)(Wt + HID * HID);            // [4][Nn]
  float* a_d      = a_s + (size_t)HEADS * Nn;
  int*   offsets  = (int*)(a_d + (size_t)HEADS * Nn);    // Nn+1
  int*   bucket_cnt    = offsets + (Nn + 1);
  int*   bucket_base   = bucket_cnt + NBMAX;
  int*   bucket_cursor = bucket_base + NBMAX;
  unsigned* tmp   = (unsigned*)(bucket_cursor + NBMAX);  // Etot u32
  int*   csr_src  = (int*)(tmp + Etot);                  // Etot

  const int nbNode = (Nn + 7) / 8;       // 6250
  const int nbEdge = (Etot + 4095) / 4096;  // 306

  transpose_w<<<HID, HID, 0, stream>>>(Wm, Wt, bucket_cnt);
  gemm_tile<<<(Nn + 31) / 32, 256, 0, stream>>>(x, Wt, att_src, att_dst,
                                                Hp, a_s, a_d, Nn);

  bucket_hist<<<nbEdge, 256, 0, stream>>>(ei, E, Etot, bucket_cnt, NB);
  scan_buckets<<<1, 512, 0, stream>>>(bucket_cnt, bucket_base, bucket_cursor,
                                      offsets, Nn, Etot, NB);
  scatter_tmp<<<nbEdge, 256, 0, stream>>>(ei, E, Etot, bucket_cursor, tmp, NB);
  csr_build<<<NB, 256, 0, stream>>>(tmp, bucket_base, bucket_cursor,
                                    offsets, csr_src, Nn);
  gat_agg2<<<HEADS * nbNode, 256, 0, stream>>>(offsets, csr_src, a_s, a_d, Hp, bias,
                                               out, Nn, nbNode);
}

// Round 13
// 155.360 us; speedup vs baseline: 1.2682x; 1.1567x over previous
//
#include <hip/hip_runtime.h>
#include <hip/hip_bf16.h>
#include <hip/hip_fp16.h>

#define HID 256
#define HEADS 4
#define DH 64
#define SLOPE 0.2f
#define NBMAX 512   // max buckets (Nn<=65536)
#define BCAP 4096   // fixed capacity per bucket (Poisson(3200)+15 sigma)

typedef __attribute__((ext_vector_type(8))) _Float16 f16x8;
typedef __attribute__((ext_vector_type(4))) float f32x4;

__device__ inline float leaky(float x) { return x >= 0.f ? x : SLOPE * x; }

// ---------- K0: Wt[n][k] = fp16(W[k][n]); block 0 zeros bucket_cursor ----------
__global__ __launch_bounds__(256) void transpose_w(const float* __restrict__ W,
                                                   _Float16* __restrict__ Wt,
                                                   int* __restrict__ bucket_cursor) {
  int n = blockIdx.x;
  int k = threadIdx.x;
  Wt[n * HID + k] = (_Float16)W[(size_t)k * HID + n];
  if (n == 0) {
    bucket_cursor[k] = 0;
    bucket_cursor[k + 256] = 0;
  }
}

// ---------- K1: FUSED  [scatter blocks (bid < nbEdge)] + [gemm blocks] ----------
// scatter: LDS-aggregated reservation into fixed-capacity bucket runs of tmp.
// gemm: 32-row A-tile staged once in LDS, B from L2-resident Wt, fused a_s/a_d.
__global__ __launch_bounds__(256) void fused_gemm_scatter(
    const float* __restrict__ X, const _Float16* __restrict__ Wt,
    const float* __restrict__ att_src, const float* __restrict__ att_dst,
    _Float16* __restrict__ Hp, float* __restrict__ a_s, float* __restrict__ a_d,
    const int* __restrict__ ei, int E, int Etot,
    int* __restrict__ bucket_cursor, unsigned* __restrict__ tmp,
    int NB, int nbEdge, int M) {
  __shared__ __align__(16) char smem[20480];   // gemm: 20KB sA | scatter: 4KB h/cur
  const int t = threadIdx.x;

  if ((int)blockIdx.x < nbEdge) {
    // ================= scatter body =================
    int* h = (int*)smem;
    int* cur = h + NBMAX;
    for (int i = t; i < NB; i += 256) h[i] = 0;
    __syncthreads();
    const int g0 = blockIdx.x * 1024;
#pragma unroll
    for (int j = 0; j < 4; ++j) {
      const int e0 = (g0 + j * 256 + t) * 4;
      if (e0 >= Etot) continue;
      if (e0 >= E) {
#pragma unroll
        for (int k = 0; k < 4; ++k) atomicAdd(&h[(e0 - E + k) >> 7], 1);
      } else {
        const int4 d4 = *(const int4*)(ei + E + e0);
        atomicAdd(&h[d4.x >> 7], 1);
        atomicAdd(&h[d4.y >> 7], 1);
        atomicAdd(&h[d4.z >> 7], 1);
        atomicAdd(&h[d4.w >> 7], 1);
      }
    }
    __syncthreads();
    for (int i = t; i < NB; i += 256)
      cur[i] = h[i] ? (i * BCAP + atomicAdd(&bucket_cursor[i], h[i])) : 0;
    __syncthreads();
#pragma unroll
    for (int j = 0; j < 4; ++j) {
      const int e0 = (g0 + j * 256 + t) * 4;
      if (e0 >= Etot) continue;
      int s[4], dn[4];
      if (e0 >= E) {
#pragma unroll
        for (int k = 0; k < 4; ++k) { s[k] = e0 - E + k; dn[k] = s[k]; }
      } else {
        const int4 s4 = *(const int4*)(ei + e0);
        const int4 d4 = *(const int4*)(ei + E + e0);
        s[0] = s4.x; s[1] = s4.y; s[2] = s4.z; s[3] = s4.w;
        dn[0] = d4.x; dn[1] = d4.y; dn[2] = d4.z; dn[3] = d4.w;
      }
#pragma unroll
      for (int k = 0; k < 4; ++k) {
        const int b = dn[k] >> 7;
        const int pos = atomicAdd(&cur[b], 1);
        tmp[pos] = (unsigned)s[k] | ((unsigned)(dn[k] & 127) << 16);
      }
    }
    return;
  }

  // ================= gemm body =================
  _Float16 (*sA)[32][40] = (_Float16 (*)[32][40])smem;
  const int head = t >> 6;
  const int l = t & 63;
  const int lr = l & 15;
  const int lk = l >> 4;
  const int row0 = ((int)blockIdx.x - nbEdge) * 32;

  {
    const int r = t >> 3;
    const int ksb = t & 7;
    const int gr = row0 + r;
    _Float16 tmpv[32];
    if (gr < M) {
      const float* p = X + (size_t)gr * HID + ksb * 32;
#pragma unroll
      for (int j = 0; j < 8; ++j) {
        const float4 v = *(const float4*)(p + j * 4);
        tmpv[j * 4 + 0] = (_Float16)v.x;
        tmpv[j * 4 + 1] = (_Float16)v.y;
        tmpv[j * 4 + 2] = (_Float16)v.z;
        tmpv[j * 4 + 3] = (_Float16)v.w;
      }
    } else {
#pragma unroll
      for (int j = 0; j < 32; ++j) tmpv[j] = (_Float16)0.f;
    }
#pragma unroll
    for (int j = 0; j < 4; ++j)
      *(uint4*)&sA[ksb][r][j * 8] = *(const uint4*)&tmpv[j * 8];
  }
  __syncthreads();

  f32x4 acc[2][4] = {};
#pragma unroll
  for (int ks = 0; ks < 8; ++ks) {
    f16x8 af[2];
#pragma unroll
    for (int mt = 0; mt < 2; ++mt)
      af[mt] = *(const f16x8*)&sA[ks][mt * 16 + lr][lk * 8];
#pragma unroll
    for (int nt = 0; nt < 4; ++nt) {
      const f16x8 bfr = *(const f16x8*)(Wt + (size_t)(head * 64 + nt * 16 + lr) * HID
                                        + ks * 32 + lk * 8);
#pragma unroll
      for (int mt = 0; mt < 2; ++mt)
        acc[mt][nt] = __builtin_amdgcn_mfma_f32_16x16x32_f16(af[mt], bfr, acc[mt][nt], 0, 0, 0);
    }
  }

  float as_v[4], ad_v[4];
#pragma unroll
  for (int nt = 0; nt < 4; ++nt) {
    as_v[nt] = att_src[head * DH + nt * 16 + lr];
    ad_v[nt] = att_dst[head * DH + nt * 16 + lr];
  }
#pragma unroll
  for (int mt = 0; mt < 2; ++mt) {
#pragma unroll
    for (int reg = 0; reg < 4; ++reg) {
      float ps = 0.f, pd = 0.f;
#pragma unroll
      for (int nt = 0; nt < 4; ++nt) {
        ps += acc[mt][nt][reg] * as_v[nt];
        pd += acc[mt][nt][reg] * ad_v[nt];
      }
#pragma unroll
      for (int off = 1; off < 16; off <<= 1) {
        ps += __shfl_xor(ps, off, 64);
        pd += __shfl_xor(pd, off, 64);
      }
      const int row = row0 + mt * 16 + lk * 4 + reg;
      if (lr == 0 && row < M) {
        a_s[(size_t)head * M + row] = ps;
        a_d[(size_t)head * M + row] = pd;
      }
    }
  }

#pragma unroll
  for (int mt = 0; mt < 2; ++mt) {
#pragma unroll
    for (int nt = 0; nt < 4; ++nt) {
      const int dh = nt * 16 + lr;
#pragma unroll
      for (int reg = 0; reg < 4; ++reg) {
        const int row = row0 + mt * 16 + lk * 4 + reg;
        if (row < M)
          Hp[((size_t)head * M + row) * DH + dh] = (_Float16)acc[mt][nt][reg];
      }
    }
  }
}

// ---------- K2: per-bucket counting sort -> csr_src + per-node starts/ends ----------
__global__ __launch_bounds__(256) void csr_build(const unsigned* __restrict__ tmp,
                                                 const int* __restrict__ bucket_cursor,
                                                 int* __restrict__ starts,
                                                 int* __restrict__ ends,
                                                 int* __restrict__ csr_src, int Nn) {
  __shared__ int h[128], cur[128];
  __shared__ int cs[BCAP];
  const int b = blockIdx.x;
  const int base = b * BCAP;
  const int cnt = min(bucket_cursor[b], BCAP);
  const int tid = threadIdx.x;
  if (tid < 128) h[tid] = 0;
  __syncthreads();
  for (int i = tid; i < cnt; i += 256)
    atomicAdd(&h[tmp[base + i] >> 16], 1);
  __syncthreads();
  const int own = (tid < 128) ? h[tid] : 0;
#pragma unroll
  for (int off = 1; off < 128; off <<= 1) {
    const int t = (tid < 128 && tid >= off) ? h[tid - off] : 0;
    __syncthreads();
    if (tid < 128) h[tid] += t;
    __syncthreads();
  }
  if (tid < 128) {
    const int excl = h[tid] - own;
    cur[tid] = excl;
    const int n = b * 128 + tid;
    if (n < Nn) {
      starts[n] = base + excl;
      ends[n] = base + excl + own;
    }
  }
  __syncthreads();
  for (int i = tid; i < cnt; i += 256) {
    const unsigned p = tmp[base + i];
    const int pos = atomicAdd(&cur[p >> 16], 1);
    cs[pos] = (int)(p & 0xffffu);
  }
  __syncthreads();
  for (int i = tid; i < cnt; i += 256)
    csr_src[base + i] = cs[i];
}

// ---------- K3: fused softmax + aggregate, head-split (head-major Hp) ----------
__global__ __launch_bounds__(256) void gat_agg2(const int* __restrict__ starts,
                                                const int* __restrict__ ends,
                                                const int* __restrict__ csr_src,
                                                const float* __restrict__ a_s,
                                                const float* __restrict__ a_d,
                                                const _Float16* __restrict__ Hp,
                                                const float* __restrict__ bias,
                                                float* __restrict__ out, int Nn, int nbNode) {
  const int head = blockIdx.x / nbNode;
  const int nb   = blockIdx.x - head * nbNode;
  const int wave = threadIdx.x >> 6;
  const int lane = threadIdx.x & 63;
  const int half = lane >> 5;
  const int hl   = lane & 31;
  const int g2   = hl >> 3;
  const int sl   = hl & 7;
  const int n    = nb * 8 + wave * 2 + half;

  int start = 0, end = 0;
  if (n < Nn) { start = starts[n]; end = ends[n]; }
  const float* __restrict__ as_h = a_s + (size_t)head * Nn;
  const float adn = (n < Nn) ? a_d[(size_t)head * Nn + n] : 0.f;
  const _Float16* __restrict__ Hh = Hp + (size_t)head * Nn * DH + sl * 8;

  float m = -INFINITY, l = 0.f;
  __half2 acc[4];
#pragma unroll
  for (int j = 0; j < 4; ++j) acc[j] = __float2half2_rn(0.f);

  const int nChunk = (end - start + 31) >> 5;
  for (int c = 0; c < nChunk; ++c) {
    const int base = start + c * 32;
    const int cnt = min(32, end - base);
    const int idx = min(base + hl, end - 1);
    const int src = csr_src[idx];
    const float lg = leaky(as_h[src] + adn);
    const float logit = (hl < cnt) ? lg : -INFINITY;

    float cm = logit;
#pragma unroll
    for (int off = 16; off > 0; off >>= 1) cm = fmaxf(cm, __shfl_xor(cm, off, 64));
    const float nm = fmaxf(m, cm);
    const float scale = __expf(m - nm);
    const __half2 s2 = __float2half2_rn(scale);
#pragma unroll
    for (int j = 0; j < 4; ++j) acc[j] = __hmul2(acc[j], s2);
    l *= scale;
    const float p = __expf(logit - nm);
    float psum = p;
#pragma unroll
    for (int off = 16; off > 0; off >>= 1) psum += __shfl_xor(psum, off, 64);
    l += psum;
    m = nm;

    const unsigned combo = (unsigned)src |
                           ((unsigned)__half_as_ushort(__float2half(p)) << 16);
    const int nIt = (cnt + 3) >> 2;
#pragma unroll 4
    for (int i = 0; i < nIt; ++i) {
      const int e = i * 4 + g2;
      const unsigned cc = (unsigned)__shfl((int)combo, half * 32 + e, 64);
      const unsigned se = cc & 0xffffu;
      const __half ah = __ushort_as_half((unsigned short)(cc >> 16));
      const __half2 a2 = __halves2half2(ah, ah);
      const uint4 hv = *(const uint4*)(Hh + (size_t)se * DH);
      acc[0] = __hfma2(a2, *(const __half2*)&hv.x, acc[0]);
      acc[1] = __hfma2(a2, *(const __half2*)&hv.y, acc[1]);
      acc[2] = __hfma2(a2, *(const __half2*)&hv.z, acc[2]);
      acc[3] = __hfma2(a2, *(const __half2*)&hv.w, acc[3]);
    }
  }
#pragma unroll
  for (int off = 8; off <= 16; off <<= 1)
#pragma unroll
    for (int j = 0; j < 4; ++j) {
      int tbits = __shfl_xor(*(const int*)&acc[j], off, 64);
      acc[j] = __hadd2(acc[j], *(const __half2*)&tbits);
    }

  if (hl < 8 && n < Nn) {
    const float inv = 1.f / (l + 1e-16f);
    float v[8];
#pragma unroll
    for (int j = 0; j < 4; ++j) {
      v[2 * j]     = __low2float(acc[j]);
      v[2 * j + 1] = __high2float(acc[j]);
    }
#pragma unroll
    for (int j = 0; j < 8; ++j)
      v[j] = fmaxf(v[j] * inv + bias[head * DH + sl * 8 + j], 0.f);
    float* op = out + (size_t)n * HID + head * DH + sl * 8;
    *(float4*)op = make_float4(v[0], v[1], v[2], v[3]);
    *(float4*)(op + 4) = make_float4(v[4], v[5], v[6], v[7]);
  }
}

extern "C" void kernel_launch(void* const* d_in, const int* in_sizes, int n_in,
                              void* d_out, int out_size, void* d_ws, size_t ws_size,
                              hipStream_t stream) {
  const float* x       = (const float*)d_in[0];
  const float* Wm      = (const float*)d_in[1];
  const float* att_src = (const float*)d_in[2];
  const float* att_dst = (const float*)d_in[3];
  const float* bias    = (const float*)d_in[4];
  const int*   ei      = (const int*)d_in[5];

  const int Nn   = in_sizes[0] / HID;   // 50000
  const int E    = in_sizes[5] / 2;     // 1200000
  const int Etot = E + Nn;              // 1250000
  const int NB   = (Nn + 127) >> 7;     // 391

  float* out = (float*)d_out;

  _Float16* Hp    = (_Float16*)d_ws;                     // [4][Nn][64] fp16
  _Float16* Wt    = Hp + (size_t)HEADS * Nn * DH;        // 256*256 fp16
  float* a_s      = (float*)(Wt + HID * HID);            // [4][Nn]
  float* a_d      = a_s + (size_t)HEADS * Nn;
  int*   starts   = (int*)(a_d + (size_t)HEADS * Nn);    // Nn
  int*   ends     = starts + Nn;                         // Nn
  int*   bucket_cursor = ends + Nn;                      // 512
  unsigned* tmp   = (unsigned*)(bucket_cursor + NBMAX);  // NB*BCAP u32
  int*   csr_src  = (int*)(tmp + (size_t)NB * BCAP);     // NB*BCAP

  const int nbNode = (Nn + 7) / 8;          // 6250
  const int nbEdge = (Etot + 4095) / 4096;  // 306
  const int nbGemm = (Nn + 31) / 32;        // 1563

  transpose_w<<<HID, HID, 0, stream>>>(Wm, Wt, bucket_cursor);
  fused_gemm_scatter<<<nbEdge + nbGemm, 256, 0, stream>>>(
      x, Wt, att_src, att_dst, Hp, a_s, a_d,
      ei, E, Etot, bucket_cursor, tmp, NB, nbEdge, Nn);
  csr_build<<<NB, 256, 0, stream>>>(tmp, bucket_cursor, starts, ends, csr_src, Nn);
  gat_agg2<<<HEADS * nbNode, 256, 0, stream>>>(starts, ends, csr_src, a_s, a_d,
                                               Hp, bias, out, Nn, nbNode);
}

// Round 14
// 146.653 us; speedup vs baseline: 1.3435x; 1.0594x over previous
//
#include <hip/hip_runtime.h>
#include <hip/hip_bf16.h>
#include <hip/hip_fp16.h>

#define HID 256
#define HEADS 4
#define DH 64
#define SLOPE 0.2f
#define NBMAX 512   // max buckets (Nn<=65536)
#define BCAP 4096   // fixed capacity per bucket (Poisson(3200)+15 sigma)

typedef __attribute__((ext_vector_type(8))) _Float16 f16x8;
typedef __attribute__((ext_vector_type(4))) float f32x4;

__device__ inline float leaky(float x) { return x >= 0.f ? x : SLOPE * x; }

// ---------- K0: Wt[n][k] = fp16(W[k][n]); block 0 zeros bucket_cursor ----------
__global__ __launch_bounds__(256) void transpose_w(const float* __restrict__ W,
                                                   _Float16* __restrict__ Wt,
                                                   int* __restrict__ bucket_cursor) {
  int n = blockIdx.x;
  int k = threadIdx.x;
  Wt[n * HID + k] = (_Float16)W[(size_t)k * HID + n];
  if (n == 0) {
    bucket_cursor[k] = 0;
    bucket_cursor[k + 256] = 0;
  }
}

// ---------- K1: FUSED  [scatter blocks (bid < nbEdge)] + [gemm blocks] ----------
// a_s/a_d now NODE-MAJOR: as4[n*4+head].
__global__ __launch_bounds__(256) void fused_gemm_scatter(
    const float* __restrict__ X, const _Float16* __restrict__ Wt,
    const float* __restrict__ att_src, const float* __restrict__ att_dst,
    _Float16* __restrict__ Hp, float* __restrict__ as4, float* __restrict__ ad4,
    const int* __restrict__ ei, int E, int Etot,
    int* __restrict__ bucket_cursor, unsigned* __restrict__ tmp,
    int NB, int nbEdge, int M) {
  __shared__ __align__(16) char smem[20480];
  const int t = threadIdx.x;

  if ((int)blockIdx.x < nbEdge) {
    // ================= scatter body =================
    int* h = (int*)smem;
    int* cur = h + NBMAX;
    for (int i = t; i < NB; i += 256) h[i] = 0;
    __syncthreads();
    const int g0 = blockIdx.x * 1024;
#pragma unroll
    for (int j = 0; j < 4; ++j) {
      const int e0 = (g0 + j * 256 + t) * 4;
      if (e0 >= Etot) continue;
      if (e0 >= E) {
#pragma unroll
        for (int k = 0; k < 4; ++k) atomicAdd(&h[(e0 - E + k) >> 7], 1);
      } else {
        const int4 d4 = *(const int4*)(ei + E + e0);
        atomicAdd(&h[d4.x >> 7], 1);
        atomicAdd(&h[d4.y >> 7], 1);
        atomicAdd(&h[d4.z >> 7], 1);
        atomicAdd(&h[d4.w >> 7], 1);
      }
    }
    __syncthreads();
    for (int i = t; i < NB; i += 256)
      cur[i] = h[i] ? (i * BCAP + atomicAdd(&bucket_cursor[i], h[i])) : 0;
    __syncthreads();
#pragma unroll
    for (int j = 0; j < 4; ++j) {
      const int e0 = (g0 + j * 256 + t) * 4;
      if (e0 >= Etot) continue;
      int s[4], dn[4];
      if (e0 >= E) {
#pragma unroll
        for (int k = 0; k < 4; ++k) { s[k] = e0 - E + k; dn[k] = s[k]; }
      } else {
        const int4 s4 = *(const int4*)(ei + e0);
        const int4 d4 = *(const int4*)(ei + E + e0);
        s[0] = s4.x; s[1] = s4.y; s[2] = s4.z; s[3] = s4.w;
        dn[0] = d4.x; dn[1] = d4.y; dn[2] = d4.z; dn[3] = d4.w;
      }
#pragma unroll
      for (int k = 0; k < 4; ++k) {
        const int b = dn[k] >> 7;
        const int pos = atomicAdd(&cur[b], 1);
        tmp[pos] = (unsigned)s[k] | ((unsigned)(dn[k] & 127) << 16);
      }
    }
    return;
  }

  // ================= gemm body =================
  _Float16 (*sA)[32][40] = (_Float16 (*)[32][40])smem;
  const int head = t >> 6;
  const int l = t & 63;
  const int lr = l & 15;
  const int lk = l >> 4;
  const int row0 = ((int)blockIdx.x - nbEdge) * 32;

  {
    const int r = t >> 3;
    const int ksb = t & 7;
    const int gr = row0 + r;
    _Float16 tmpv[32];
    if (gr < M) {
      const float* p = X + (size_t)gr * HID + ksb * 32;
#pragma unroll
      for (int j = 0; j < 8; ++j) {
        const float4 v = *(const float4*)(p + j * 4);
        tmpv[j * 4 + 0] = (_Float16)v.x;
        tmpv[j * 4 + 1] = (_Float16)v.y;
        tmpv[j * 4 + 2] = (_Float16)v.z;
        tmpv[j * 4 + 3] = (_Float16)v.w;
      }
    } else {
#pragma unroll
      for (int j = 0; j < 32; ++j) tmpv[j] = (_Float16)0.f;
    }
#pragma unroll
    for (int j = 0; j < 4; ++j)
      *(uint4*)&sA[ksb][r][j * 8] = *(const uint4*)&tmpv[j * 8];
  }
  __syncthreads();

  f32x4 acc[2][4] = {};
#pragma unroll
  for (int ks = 0; ks < 8; ++ks) {
    f16x8 af[2];
#pragma unroll
    for (int mt = 0; mt < 2; ++mt)
      af[mt] = *(const f16x8*)&sA[ks][mt * 16 + lr][lk * 8];
#pragma unroll
    for (int nt = 0; nt < 4; ++nt) {
      const f16x8 bfr = *(const f16x8*)(Wt + (size_t)(head * 64 + nt * 16 + lr) * HID
                                        + ks * 32 + lk * 8);
#pragma unroll
      for (int mt = 0; mt < 2; ++mt)
        acc[mt][nt] = __builtin_amdgcn_mfma_f32_16x16x32_f16(af[mt], bfr, acc[mt][nt], 0, 0, 0);
    }
  }

  float as_v[4], ad_v[4];
#pragma unroll
  for (int nt = 0; nt < 4; ++nt) {
    as_v[nt] = att_src[head * DH + nt * 16 + lr];
    ad_v[nt] = att_dst[head * DH + nt * 16 + lr];
  }
#pragma unroll
  for (int mt = 0; mt < 2; ++mt) {
#pragma unroll
    for (int reg = 0; reg < 4; ++reg) {
      float ps = 0.f, pd = 0.f;
#pragma unroll
      for (int nt = 0; nt < 4; ++nt) {
        ps += acc[mt][nt][reg] * as_v[nt];
        pd += acc[mt][nt][reg] * ad_v[nt];
      }
#pragma unroll
      for (int off = 1; off < 16; off <<= 1) {
        ps += __shfl_xor(ps, off, 64);
        pd += __shfl_xor(pd, off, 64);
      }
      const int row = row0 + mt * 16 + lk * 4 + reg;
      if (lr == 0 && row < M) {
        as4[(size_t)row * 4 + head] = ps;   // node-major
        ad4[(size_t)row * 4 + head] = pd;
      }
    }
  }

#pragma unroll
  for (int mt = 0; mt < 2; ++mt) {
#pragma unroll
    for (int nt = 0; nt < 4; ++nt) {
      const int dh = nt * 16 + lr;
#pragma unroll
      for (int reg = 0; reg < 4; ++reg) {
        const int row = row0 + mt * 16 + lk * 4 + reg;
        if (row < M)
          Hp[((size_t)head * M + row) * DH + dh] = (_Float16)acc[mt][nt][reg];
      }
    }
  }
}

// ---------- K2: counting sort + a_s fusion -> per-head csr entries ----------
// csr_h[head][pos] = src | fp16(a_s[src][head])<<16
__global__ __launch_bounds__(256) void csr_build(const unsigned* __restrict__ tmp,
                                                 const int* __restrict__ bucket_cursor,
                                                 int* __restrict__ starts,
                                                 int* __restrict__ ends,
                                                 unsigned* __restrict__ csr_h,
                                                 const float4* __restrict__ as4,
                                                 int Nn, int csrStride) {
  __shared__ int h[128], cur[128];
  __shared__ int cs[BCAP];
  const int b = blockIdx.x;
  const int base = b * BCAP;
  const int cnt = min(bucket_cursor[b], BCAP);
  const int tid = threadIdx.x;
  if (tid < 128) h[tid] = 0;
  __syncthreads();
  for (int i = tid; i < cnt; i += 256)
    atomicAdd(&h[tmp[base + i] >> 16], 1);
  __syncthreads();
  const int own = (tid < 128) ? h[tid] : 0;
#pragma unroll
  for (int off = 1; off < 128; off <<= 1) {
    const int t = (tid < 128 && tid >= off) ? h[tid - off] : 0;
    __syncthreads();
    if (tid < 128) h[tid] += t;
    __syncthreads();
  }
  if (tid < 128) {
    const int excl = h[tid] - own;
    cur[tid] = excl;
    const int n = b * 128 + tid;
    if (n < Nn) {
      starts[n] = base + excl;
      ends[n] = base + excl + own;
    }
  }
  __syncthreads();
  for (int i = tid; i < cnt; i += 256) {
    const unsigned p = tmp[base + i];
    const int pos = atomicAdd(&cur[p >> 16], 1);
    cs[pos] = (int)(p & 0xffffu);
  }
  __syncthreads();
  for (int i = tid; i < cnt; i += 256) {
    const int src = cs[i];
    const float4 a = as4[src];
    csr_h[base + i] = (unsigned)src |
                      ((unsigned)__half_as_ushort(__float2half(a.x)) << 16);
    csr_h[csrStride + base + i] = (unsigned)src |
                      ((unsigned)__half_as_ushort(__float2half(a.y)) << 16);
    csr_h[2 * csrStride + base + i] = (unsigned)src |
                      ((unsigned)__half_as_ushort(__float2half(a.z)) << 16);
    csr_h[3 * csrStride + base + i] = (unsigned)src |
                      ((unsigned)__half_as_ushort(__float2half(a.w)) << 16);
  }
}

// ---------- K3: softmax (no-max, deferred sum) + aggregate ----------
__global__ __launch_bounds__(256) void gat_agg2(const int* __restrict__ starts,
                                                const int* __restrict__ ends,
                                                const unsigned* __restrict__ csr_h,
                                                const float* __restrict__ ad4,
                                                const _Float16* __restrict__ Hp,
                                                const float* __restrict__ bias,
                                                float* __restrict__ out,
                                                int Nn, int nbNode, int csrStride) {
  const int head = blockIdx.x / nbNode;
  const int nb   = blockIdx.x - head * nbNode;
  const int wave = threadIdx.x >> 6;
  const int lane = threadIdx.x & 63;
  const int half = lane >> 5;
  const int hl   = lane & 31;
  const int g2   = hl >> 3;
  const int sl   = hl & 7;
  const int n    = nb * 8 + wave * 2 + half;

  int start = 0, end = 0;
  if (n < Nn) { start = starts[n]; end = ends[n]; }
  const unsigned* __restrict__ ch = csr_h + (size_t)head * csrStride;
  const float adn = (n < Nn) ? ad4[(size_t)n * 4 + head] : 0.f;
  const _Float16* __restrict__ Hh = Hp + (size_t)head * Nn * DH + sl * 8;

  float lpart = 0.f;
  __half2 acc[4];
#pragma unroll
  for (int j = 0; j < 4; ++j) acc[j] = __float2half2_rn(0.f);

  const int nChunk = (end - start + 31) >> 5;
  for (int c = 0; c < nChunk; ++c) {
    const int base = start + c * 32;
    const int cnt = min(32, end - base);
    const int idx = min(base + hl, end - 1);
    const unsigned ce = ch[idx];
    const float asv = __half2float(__ushort_as_half((unsigned short)(ce >> 16)));
    const float p = (hl < cnt) ? __expf(leaky(asv + adn)) : 0.f;
    lpart += p;

    const unsigned combo = (ce & 0xffffu) |
                           ((unsigned)__half_as_ushort(__float2half(p)) << 16);
    const int nIt = (cnt + 3) >> 2;
#pragma unroll 4
    for (int i = 0; i < nIt; ++i) {
      const int e = i * 4 + g2;
      const unsigned cc = (unsigned)__shfl((int)combo, half * 32 + e, 64);
      const unsigned se = cc & 0xffffu;
      const __half ah = __ushort_as_half((unsigned short)(cc >> 16));
      const __half2 a2 = __halves2half2(ah, ah);
      const uint4 hv = *(const uint4*)(Hh + (size_t)se * DH);
      acc[0] = __hfma2(a2, *(const __half2*)&hv.x, acc[0]);
      acc[1] = __hfma2(a2, *(const __half2*)&hv.y, acc[1]);
      acc[2] = __hfma2(a2, *(const __half2*)&hv.z, acc[2]);
      acc[3] = __hfma2(a2, *(const __half2*)&hv.w, acc[3]);
    }
  }
  // deferred softmax-denominator reduce (within half)
#pragma unroll
  for (int off = 16; off > 0; off >>= 1) lpart += __shfl_xor(lpart, off, 64);
  // cross-subgroup acc reduce (within half)
#pragma unroll
  for (int off = 8; off <= 16; off <<= 1)
#pragma unroll
    for (int j = 0; j < 4; ++j) {
      int tbits = __shfl_xor(*(const int*)&acc[j], off, 64);
      acc[j] = __hadd2(acc[j], *(const __half2*)&tbits);
    }

  if (hl < 8 && n < Nn) {
    const float inv = 1.f / (lpart + 1e-16f);
    float v[8];
#pragma unroll
    for (int j = 0; j < 4; ++j) {
      v[2 * j]     = __low2float(acc[j]);
      v[2 * j + 1] = __high2float(acc[j]);
    }
#pragma unroll
    for (int j = 0; j < 8; ++j)
      v[j] = fmaxf(v[j] * inv + bias[head * DH + sl * 8 + j], 0.f);
    float* op = out + (size_t)n * HID + head * DH + sl * 8;
    *(float4*)op = make_float4(v[0], v[1], v[2], v[3]);
    *(float4*)(op + 4) = make_float4(v[4], v[5], v[6], v[7]);
  }
}

extern "C" void kernel_launch(void* const* d_in, const int* in_sizes, int n_in,
                              void* d_out, int out_size, void* d_ws, size_t ws_size,
                              hipStream_t stream) {
  const float* x       = (const float*)d_in[0];
  const float* Wm      = (const float*)d_in[1];
  const float* att_src = (const float*)d_in[2];
  const float* att_dst = (const float*)d_in[3];
  const float* bias    = (const float*)d_in[4];
  const int*   ei      = (const int*)d_in[5];

  const int Nn   = in_sizes[0] / HID;   // 50000
  const int E    = in_sizes[5] / 2;     // 1200000
  const int Etot = E + Nn;              // 1250000
  const int NB   = (Nn + 127) >> 7;     // 391
  const int csrStride = NB * BCAP;

  float* out = (float*)d_out;

  _Float16* Hp    = (_Float16*)d_ws;                     // [4][Nn][64] fp16
  _Float16* Wt    = Hp + (size_t)HEADS * Nn * DH;        // 256*256 fp16
  float* as4      = (float*)(Wt + HID * HID);            // [Nn][4]
  float* ad4      = as4 + (size_t)Nn * 4;                // [Nn][4]
  int*   starts   = (int*)(ad4 + (size_t)Nn * 4);        // Nn
  int*   ends     = starts + Nn;                         // Nn
  int*   bucket_cursor = ends + Nn;                      // 512
  unsigned* tmp   = (unsigned*)(bucket_cursor + NBMAX);  // NB*BCAP u32
  unsigned* csr_h = tmp + (size_t)csrStride;             // [4][NB*BCAP] u32

  const int nbNode = (Nn + 7) / 8;          // 6250
  const int nbEdge = (Etot + 4095) / 4096;  // 306
  const int nbGemm = (Nn + 31) / 32;        // 1563

  transpose_w<<<HID, HID, 0, stream>>>(Wm, Wt, bucket_cursor);
  fused_gemm_scatter<<<nbEdge + nbGemm, 256, 0, stream>>>(
      x, Wt, att_src, att_dst, Hp, as4, ad4,
      ei, E, Etot, bucket_cursor, tmp, NB, nbEdge, Nn);
  csr_build<<<NB, 256, 0, stream>>>(tmp, bucket_cursor, starts, ends, csr_h,
                                    (const float4*)as4, Nn, csrStride);
  gat_agg2<<<HEADS * nbNode, 256, 0, stream>>>(starts, ends, csr_h, ad4,
                                               Hp, bias, out, Nn, nbNode, csrStride);
}

// Round 15
// 146.608 us; speedup vs baseline: 1.3439x; 1.0003x over previous
//
#include <hip/hip_runtime.h>
#include <hip/hip_bf16.h>
#include <hip/hip_fp16.h>

#define HID 256
#define HEADS 4
#define DH 64
#define SLOPE 0.2f
#define NBMAX 512   // max buckets (Nn<=65536)
#define BCAP 4096   // fixed capacity per bucket (Poisson(3200)+15 sigma)

typedef __attribute__((ext_vector_type(8))) _Float16 f16x8;
typedef __attribute__((ext_vector_type(4))) float f32x4;

__device__ inline float leaky(float x) { return x >= 0.f ? x : SLOPE * x; }

// ---------- K0: Wt[n][k] = fp16(W[k][n]); block 0 zeros bucket_cursor ----------
__global__ __launch_bounds__(256) void transpose_w(const float* __restrict__ W,
                                                   _Float16* __restrict__ Wt,
                                                   int* __restrict__ bucket_cursor) {
  int n = blockIdx.x;
  int k = threadIdx.x;
  Wt[n * HID + k] = (_Float16)W[(size_t)k * HID + n];
  if (n == 0) {
    bucket_cursor[k] = 0;
    bucket_cursor[k + 256] = 0;
  }
}

// ---------- K1: FUSED  [scatter blocks (bid < nbEdge)] + [gemm blocks] ----------
__global__ __launch_bounds__(256) void fused_gemm_scatter(
    const float* __restrict__ X, const _Float16* __restrict__ Wt,
    const float* __restrict__ att_src, const float* __restrict__ att_dst,
    _Float16* __restrict__ Hp, float* __restrict__ as4, float* __restrict__ ad4,
    const int* __restrict__ ei, int E, int Etot,
    int* __restrict__ bucket_cursor, unsigned* __restrict__ tmp,
    int NB, int nbEdge, int M) {
  __shared__ __align__(16) char smem[20480];
  const int t = threadIdx.x;

  if ((int)blockIdx.x < nbEdge) {
    // ================= scatter body =================
    int* h = (int*)smem;
    int* cur = h + NBMAX;
    for (int i = t; i < NB; i += 256) h[i] = 0;
    __syncthreads();
    const int g0 = blockIdx.x * 1024;
#pragma unroll
    for (int j = 0; j < 4; ++j) {
      const int e0 = (g0 + j * 256 + t) * 4;
      if (e0 >= Etot) continue;
      if (e0 >= E) {
#pragma unroll
        for (int k = 0; k < 4; ++k) atomicAdd(&h[(e0 - E + k) >> 7], 1);
      } else {
        const int4 d4 = *(const int4*)(ei + E + e0);
        atomicAdd(&h[d4.x >> 7], 1);
        atomicAdd(&h[d4.y >> 7], 1);
        atomicAdd(&h[d4.z >> 7], 1);
        atomicAdd(&h[d4.w >> 7], 1);
      }
    }
    __syncthreads();
    for (int i = t; i < NB; i += 256)
      cur[i] = h[i] ? (i * BCAP + atomicAdd(&bucket_cursor[i], h[i])) : 0;
    __syncthreads();
#pragma unroll
    for (int j = 0; j < 4; ++j) {
      const int e0 = (g0 + j * 256 + t) * 4;
      if (e0 >= Etot) continue;
      int s[4], dn[4];
      if (e0 >= E) {
#pragma unroll
        for (int k = 0; k < 4; ++k) { s[k] = e0 - E + k; dn[k] = s[k]; }
      } else {
        const int4 s4 = *(const int4*)(ei + e0);
        const int4 d4 = *(const int4*)(ei + E + e0);
        s[0] = s4.x; s[1] = s4.y; s[2] = s4.z; s[3] = s4.w;
        dn[0] = d4.x; dn[1] = d4.y; dn[2] = d4.z; dn[3] = d4.w;
      }
#pragma unroll
      for (int k = 0; k < 4; ++k) {
        const int b = dn[k] >> 7;
        const int pos = atomicAdd(&cur[b], 1);
        tmp[pos] = (unsigned)s[k] | ((unsigned)(dn[k] & 127) << 16);
      }
    }
    return;
  }

  // ================= gemm body =================
  _Float16 (*sA)[32][40] = (_Float16 (*)[32][40])smem;
  const int head = t >> 6;
  const int l = t & 63;
  const int lr = l & 15;
  const int lk = l >> 4;
  const int row0 = ((int)blockIdx.x - nbEdge) * 32;

  {
    const int r = t >> 3;
    const int ksb = t & 7;
    const int gr = row0 + r;
    _Float16 tmpv[32];
    if (gr < M) {
      const float* p = X + (size_t)gr * HID + ksb * 32;
#pragma unroll
      for (int j = 0; j < 8; ++j) {
        const float4 v = *(const float4*)(p + j * 4);
        tmpv[j * 4 + 0] = (_Float16)v.x;
        tmpv[j * 4 + 1] = (_Float16)v.y;
        tmpv[j * 4 + 2] = (_Float16)v.z;
        tmpv[j * 4 + 3] = (_Float16)v.w;
      }
    } else {
#pragma unroll
      for (int j = 0; j < 32; ++j) tmpv[j] = (_Float16)0.f;
    }
#pragma unroll
    for (int j = 0; j < 4; ++j)
      *(uint4*)&sA[ksb][r][j * 8] = *(const uint4*)&tmpv[j * 8];
  }
  __syncthreads();

  f32x4 acc[2][4] = {};
#pragma unroll
  for (int ks = 0; ks < 8; ++ks) {
    f16x8 af[2];
#pragma unroll
    for (int mt = 0; mt < 2; ++mt)
      af[mt] = *(const f16x8*)&sA[ks][mt * 16 + lr][lk * 8];
#pragma unroll
    for (int nt = 0; nt < 4; ++nt) {
      const f16x8 bfr = *(const f16x8*)(Wt + (size_t)(head * 64 + nt * 16 + lr) * HID
                                        + ks * 32 + lk * 8);
#pragma unroll
      for (int mt = 0; mt < 2; ++mt)
        acc[mt][nt] = __builtin_amdgcn_mfma_f32_16x16x32_f16(af[mt], bfr, acc[mt][nt], 0, 0, 0);
    }
  }

  float as_v[4], ad_v[4];
#pragma unroll
  for (int nt = 0; nt < 4; ++nt) {
    as_v[nt] = att_src[head * DH + nt * 16 + lr];
    ad_v[nt] = att_dst[head * DH + nt * 16 + lr];
  }
#pragma unroll
  for (int mt = 0; mt < 2; ++mt) {
#pragma unroll
    for (int reg = 0; reg < 4; ++reg) {
      float ps = 0.f, pd = 0.f;
#pragma unroll
      for (int nt = 0; nt < 4; ++nt) {
        ps += acc[mt][nt][reg] * as_v[nt];
        pd += acc[mt][nt][reg] * ad_v[nt];
      }
#pragma unroll
      for (int off = 1; off < 16; off <<= 1) {
        ps += __shfl_xor(ps, off, 64);
        pd += __shfl_xor(pd, off, 64);
      }
      const int row = row0 + mt * 16 + lk * 4 + reg;
      if (lr == 0 && row < M) {
        as4[(size_t)row * 4 + head] = ps;   // node-major
        ad4[(size_t)row * 4 + head] = pd;
      }
    }
  }

#pragma unroll
  for (int mt = 0; mt < 2; ++mt) {
#pragma unroll
    for (int nt = 0; nt < 4; ++nt) {
      const int dh = nt * 16 + lr;
#pragma unroll
      for (int reg = 0; reg < 4; ++reg) {
        const int row = row0 + mt * 16 + lk * 4 + reg;
        if (row < M)
          Hp[((size_t)head * M + row) * DH + dh] = (_Float16)acc[mt][nt][reg];
      }
    }
  }
}

// ---------- K2: counting sort + per-head p = exp(leaky(a_s+a_d)) fused ----------
// csr_h[head][pos] = src | fp16(p)<<16   (p unnormalized softmax numerator)
__global__ __launch_bounds__(256) void csr_build(const unsigned* __restrict__ tmp,
                                                 const int* __restrict__ bucket_cursor,
                                                 int* __restrict__ starts,
                                                 int* __restrict__ ends,
                                                 unsigned* __restrict__ csr_h,
                                                 const float4* __restrict__ as4,
                                                 const float4* __restrict__ ad4,
                                                 int Nn, int csrStride) {
  __shared__ int h[128], cur[128];
  __shared__ unsigned cs[BCAP];
  const int b = blockIdx.x;
  const int base = b * BCAP;
  const int cnt = min(bucket_cursor[b], BCAP);
  const int tid = threadIdx.x;
  if (tid < 128) h[tid] = 0;
  __syncthreads();
  for (int i = tid; i < cnt; i += 256)
    atomicAdd(&h[tmp[base + i] >> 16], 1);
  __syncthreads();
  const int own = (tid < 128) ? h[tid] : 0;
#pragma unroll
  for (int off = 1; off < 128; off <<= 1) {
    const int t = (tid < 128 && tid >= off) ? h[tid - off] : 0;
    __syncthreads();
    if (tid < 128) h[tid] += t;
    __syncthreads();
  }
  if (tid < 128) {
    const int excl = h[tid] - own;
    cur[tid] = excl;
    const int n = b * 128 + tid;
    if (n < Nn) {
      starts[n] = base + excl;
      ends[n] = base + excl + own;
    }
  }
  __syncthreads();
  for (int i = tid; i < cnt; i += 256) {
    const unsigned p = tmp[base + i];
    const int pos = atomicAdd(&cur[p >> 16], 1);
    cs[pos] = p;                           // keep src | dnl<<16
  }
  __syncthreads();
  for (int i = tid; i < cnt; i += 256) {
    const unsigned pe = cs[i];
    const int src = (int)(pe & 0xffffu);
    const int dnl = (int)(pe >> 16);
    const float4 a = as4[src];
    const float4 d = ad4[b * 128 + dnl];
    const float p0 = __expf(leaky(a.x + d.x));
    const float p1 = __expf(leaky(a.y + d.y));
    const float p2 = __expf(leaky(a.z + d.z));
    const float p3 = __expf(leaky(a.w + d.w));
    csr_h[base + i] = (unsigned)src |
                      ((unsigned)__half_as_ushort(__float2half(p0)) << 16);
    csr_h[csrStride + base + i] = (unsigned)src |
                      ((unsigned)__half_as_ushort(__float2half(p1)) << 16);
    csr_h[2 * csrStride + base + i] = (unsigned)src |
                      ((unsigned)__half_as_ushort(__float2half(p2)) << 16);
    csr_h[3 * csrStride + base + i] = (unsigned)src |
                      ((unsigned)__half_as_ushort(__float2half(p3)) << 16);
  }
}

// ---------- K3: aggregate with precomputed p (no logit math in-loop) ----------
__global__ __launch_bounds__(256) void gat_agg2(const int* __restrict__ starts,
                                                const int* __restrict__ ends,
                                                const unsigned* __restrict__ csr_h,
                                                const _Float16* __restrict__ Hp,
                                                const float* __restrict__ bias,
                                                float* __restrict__ out,
                                                int Nn, int nbNode, int csrStride) {
  const int head = blockIdx.x / nbNode;
  const int nb   = blockIdx.x - head * nbNode;
  const int wave = threadIdx.x >> 6;
  const int lane = threadIdx.x & 63;
  const int half = lane >> 5;
  const int hl   = lane & 31;
  const int g2   = hl >> 3;
  const int sl   = hl & 7;
  const int n    = nb * 8 + wave * 2 + half;

  int start = 0, end = 0;
  if (n < Nn) { start = starts[n]; end = ends[n]; }
  const unsigned* __restrict__ ch = csr_h + (size_t)head * csrStride;
  const _Float16* __restrict__ Hh = Hp + (size_t)head * Nn * DH + sl * 8;

  float lpart = 0.f;
  __half2 acc[4];
#pragma unroll
  for (int j = 0; j < 4; ++j) acc[j] = __float2half2_rn(0.f);

  const int nChunk = (end - start + 31) >> 5;
  for (int c = 0; c < nChunk; ++c) {
    const int base = start + c * 32;
    const int cnt = min(32, end - base);
    const int idx = min(base + hl, end - 1);
    const unsigned ce = ch[idx];
    const bool valid = hl < cnt;
    const unsigned combo = valid ? ce : (ce & 0xffffu);   // zero p for OOB lanes
    lpart += valid ? __half2float(__ushort_as_half((unsigned short)(ce >> 16))) : 0.f;

    const int nIt = (cnt + 3) >> 2;
#pragma unroll 4
    for (int i = 0; i < nIt; ++i) {
      const int e = i * 4 + g2;
      const unsigned cc = (unsigned)__shfl((int)combo, half * 32 + e, 64);
      const unsigned se = cc & 0xffffu;
      const __half ah = __ushort_as_half((unsigned short)(cc >> 16));
      const __half2 a2 = __halves2half2(ah, ah);
      const uint4 hv = *(const uint4*)(Hh + (size_t)se * DH);
      acc[0] = __hfma2(a2, *(const __half2*)&hv.x, acc[0]);
      acc[1] = __hfma2(a2, *(const __half2*)&hv.y, acc[1]);
      acc[2] = __hfma2(a2, *(const __half2*)&hv.z, acc[2]);
      acc[3] = __hfma2(a2, *(const __half2*)&hv.w, acc[3]);
    }
  }
  // softmax-denominator reduce (within half)
#pragma unroll
  for (int off = 16; off > 0; off >>= 1) lpart += __shfl_xor(lpart, off, 64);
  // cross-subgroup acc reduce (within half)
#pragma unroll
  for (int off = 8; off <= 16; off <<= 1)
#pragma unroll
    for (int j = 0; j < 4; ++j) {
      int tbits = __shfl_xor(*(const int*)&acc[j], off, 64);
      acc[j] = __hadd2(acc[j], *(const __half2*)&tbits);
    }

  if (hl < 8 && n < Nn) {
    const float inv = 1.f / (lpart + 1e-16f);
    float v[8];
#pragma unroll
    for (int j = 0; j < 4; ++j) {
      v[2 * j]     = __low2float(acc[j]);
      v[2 * j + 1] = __high2float(acc[j]);
    }
#pragma unroll
    for (int j = 0; j < 8; ++j)
      v[j] = fmaxf(v[j] * inv + bias[head * DH + sl * 8 + j], 0.f);
    float* op = out + (size_t)n * HID + head * DH + sl * 8;
    *(float4*)op = make_float4(v[0], v[1], v[2], v[3]);
    *(float4*)(op + 4) = make_float4(v[4], v[5], v[6], v[7]);
  }
}

extern "C" void kernel_launch(void* const* d_in, const int* in_sizes, int n_in,
                              void* d_out, int out_size, void* d_ws, size_t ws_size,
                              hipStream_t stream) {
  const float* x       = (const float*)d_in[0];
  const float* Wm      = (const float*)d_in[1];
  const float* att_src = (const float*)d_in[2];
  const float* att_dst = (const float*)d_in[3];
  const float* bias    = (const float*)d_in[4];
  const int*   ei      = (const int*)d_in[5];

  const int Nn   = in_sizes[0] / HID;   // 50000
  const int E    = in_sizes[5] / 2;     // 1200000
  const int Etot = E + Nn;              // 1250000
  const int NB   = (Nn + 127) >> 7;     // 391
  const int csrStride = NB * BCAP;

  float* out = (float*)d_out;

  _Float16* Hp    = (_Float16*)d_ws;                     // [4][Nn][64] fp16
  _Float16* Wt    = Hp + (size_t)HEADS * Nn * DH;        // 256*256 fp16
  float* as4      = (float*)(Wt + HID * HID);            // [Nn][4]
  float* ad4      = as4 + (size_t)Nn * 4;                // [Nn][4]
  int*   starts   = (int*)(ad4 + (size_t)Nn * 4);        // Nn
  int*   ends     = starts + Nn;                         // Nn
  int*   bucket_cursor = ends + Nn;                      // 512
  unsigned* tmp   = (unsigned*)(bucket_cursor + NBMAX);  // NB*BCAP u32
  unsigned* csr_h = tmp + (size_t)csrStride;             // [4][NB*BCAP] u32

  const int nbNode = (Nn + 7) / 8;          // 6250
  const int nbEdge = (Etot + 4095) / 4096;  // 306
  const int nbGemm = (Nn + 31) / 32;        // 1563

  transpose_w<<<HID, HID, 0, stream>>>(Wm, Wt, bucket_cursor);
  fused_gemm_scatter<<<nbEdge + nbGemm, 256, 0, stream>>>(
      x, Wt, att_src, att_dst, Hp, as4, ad4,
      ei, E, Etot, bucket_cursor, tmp, NB, nbEdge, Nn);
  csr_build<<<NB, 256, 0, stream>>>(tmp, bucket_cursor, starts, ends, csr_h,
                                    (const float4*)as4, (const float4*)ad4,
                                    Nn, csrStride);
  gat_agg2<<<HEADS * nbNode, 256, 0, stream>>>(starts, ends, csr_h,
                                               Hp, bias, out, Nn, nbNode, csrStride);
}